// Round 14
// baseline (33.714 us; speedup 1.0000x reference)
//
#include <hip/hip_runtime.h>
#include <hip/hip_bf16.h>

// ThreeWayAttention: B=32, S=128, D=32, F=32, U=11
// p_ijk ∝ EA[i,j]·EB[j,k]·EC[i,k], EX = exp(X/9), diagonals = 0.
// E computed ONCE in k_qe (global, 6.3 MB, XCD-L2-resident: batch b -> XCD b%8
// in every kernel via b = bid&31). k_qe also zeroes cnt.
// k_marg per block (b, job, cc=c-chunk of 16, kh=κ-half of 64):
//   job0: acc[i,κ]=Σ_{j∈cc} EA[i,j]EB[j,κ]; v=EC⊙acc → m1 rows, m3 cols
//   job1: acc[j,κ]=Σ_{i∈cc} EA[i,j]EC[i,κ]; v=EB⊙acc → m2 rows
// Partials -> disjoint slots via agent-scope (sc1) stores; last of the 32
// blocks per batch (cnt atomic) reads them back agent-scope and writes
// out[b] = [m1@V, m2@V, m3@V]/Z, Z = Σ m1.  No fences, no RMW data chains.

#define B_ 32
#define S_ 128
#define D_ 32
#define F_ 32
#define U_ 11
#define INV9 (1.0f / 9.0f)

// ---------------- Kernel 1: Q projections + E tiles (once) ----------------
// grid: 384 = rest*32 + b  (b, m=rest>>2, 32-row i-tile=rest&3), 256 threads.
__global__ __launch_bounds__(256) void k_qe(const float* __restrict__ X,
    const float* __restrict__ W1, const float* __restrict__ b1,
    const float* __restrict__ W2, const float* __restrict__ b2,
    const float* __restrict__ W3, const float* __restrict__ b3,
    float* __restrict__ E, unsigned int* __restrict__ cnt) {
    int blk = blockIdx.x;
    int b = blk & 31;
    int rest = blk >> 5;               // 0..11
    int m = rest >> 2;   // 0:EA(Q1,Q2) 1:EB(Q2,Q3) 2:EC(Q1,Q3)
    int tl = rest & 3;   // 32-row tile
    __shared__ float Wt[2][U_][32];    // [side][u][d]
    __shared__ float bsh[2][U_];
    __shared__ float QRt[U_][S_];      // [u][j]
    __shared__ float QLt[U_][32];      // [u][il]
    int t = threadIdx.x;

    if (rest == 0 && t == 0) cnt[b] = 0u;   // kernel-end release covers this

    const float* WL = (m == 0) ? W1 : (m == 1) ? W2 : W1;
    const float* WR = (m == 0) ? W2 : (m == 1) ? W3 : W3;
    const float* bL = (m == 0) ? b1 : (m == 1) ? b2 : b1;
    const float* bR = (m == 0) ? b2 : (m == 1) ? b3 : b3;
    for (int idx = t; idx < 704; idx += 256) {
        int side = idx >= 352;
        int r = idx - side * 352;
        int u = r >> 5, d = r & 31;
        Wt[side][u][d] = (side ? WR : WL)[d * U_ + u];
    }
    if (t < 22) {
        int side = t >= U_;
        int u = side ? t - U_ : t;
        bsh[side][u] = (side ? bR : bL)[u];
    }
    __syncthreads();

    if (t < 160) {
        int isR = (t < 128);
        int row = isR ? t : (tl * 32 + (t - 128));
        const float* Xr = X + ((size_t)b * S_ + row) * D_;
        float4 xv[8];
#pragma unroll
        for (int q = 0; q < 8; ++q) xv[q] = ((const float4*)Xr)[q];
        float qv[U_];
#pragma unroll
        for (int u = 0; u < U_; ++u) qv[u] = bsh[isR][u];
#pragma unroll
        for (int d4 = 0; d4 < 8; ++d4) {
            float4 x = xv[d4];
#pragma unroll
            for (int u = 0; u < U_; ++u) {
                float4 w = *(const float4*)&Wt[isR][u][d4 * 4];
                qv[u] += x.x * w.x + x.y * w.y + x.z * w.z + x.w * w.w;
            }
        }
        if (isR) {
#pragma unroll
            for (int u = 0; u < U_; ++u) QRt[u][t] = qv[u];
        } else {
#pragma unroll
            for (int u = 0; u < U_; ++u) QLt[u][t - 128] = qv[u];
        }
    }
    __syncthreads();

    // E phase: thread owns fixed j4; QR fragment cached in registers.
    float* Eb = E + (size_t)(b * 3 + m) * (S_ * S_);
    int j4 = (t & 31) * 4;
    int il0 = (t >> 5) * 4;
    float4 qr[U_];
#pragma unroll
    for (int u = 0; u < U_; ++u) qr[u] = *(const float4*)&QRt[u][j4];
#pragma unroll
    for (int q = 0; q < 4; ++q) {
        int il = il0 + q;
        int i = tl * 32 + il;
        float s0 = 0, s1 = 0, s2 = 0, s3v = 0;
#pragma unroll
        for (int u = 0; u < U_; ++u) {
            float ql = QLt[u][il];
            s0 += ql * qr[u].x; s1 += ql * qr[u].y;
            s2 += ql * qr[u].z; s3v += ql * qr[u].w;
        }
        float4 e;
        e.x = (j4 + 0 == i) ? 0.f : __expf(s0 * INV9);
        e.y = (j4 + 1 == i) ? 0.f : __expf(s1 * INV9);
        e.z = (j4 + 2 == i) ? 0.f : __expf(s2 * INV9);
        e.w = (j4 + 3 == i) ? 0.f : __expf(s3v * INV9);
        *(float4*)&Eb[(size_t)i * S_ + j4] = e;
    }
}

// ------- Kernel 2: marginals + last-block-per-batch output -------
// grid: 1024 = kh*512 + cc*64 + job*32 + b, 256 threads, 8x4 tile.
__global__ __launch_bounds__(256, 4) void k_marg(const float* __restrict__ E,
    float* __restrict__ m1p, float* __restrict__ m2p, float* __restrict__ m3p,
    const float* __restrict__ V, float* __restrict__ out,
    unsigned int* __restrict__ cnt) {
    int bid = blockIdx.x;
    int b   = bid & 31;
    int job = (bid >> 5) & 1;
    int cc  = (bid >> 6) & 7;          // 8 chunks of 16
    int kh  = bid >> 9;                // 0..1
    int c0  = cc * 16, kk0 = kh * 64;
    const float* EA = E + (size_t)b * 3 * S_ * S_;
    const float* EB = EA + S_ * S_;
    const float* EC = EB + S_ * S_;
    const float* Bsrc = job ? EC : EB;
    const float* Wsrc = job ? EB : EC;

    // LDS pool: B-phase At[16][132](2112)+Bs[16][68](1088); C-phase
    // Vs[128][33](4224)+ms[3][128](384)+zr[4]
    __shared__ __align__(16) float pool[4624];
    __shared__ int lastflag;
    float* At = pool;                  // [c][r] stride 132
    float* Bs = pool + 2112;           // [c][κ] stride 68
    float* red = pool;                 // m3 reduce alias (after At reads done)

    int t = threadIdx.x;

    // ---- stage At ----
    if (job == 0) {
        // At[j][i] = EA[i][c0+j] (transpose in LDS; 2-way write conflict free)
#pragma unroll
        for (int q = 0; q < 2; ++q) {
            int idx = t + q * 256;            // f4 idx 0..511
            int i  = idx >> 2;                // 0..127
            int jj = (idx & 3) * 4;           // 0..12
            float4 v = *(const float4*)&EA[(size_t)i * S_ + c0 + jj];
            At[(jj + 0) * 132 + i] = v.x; At[(jj + 1) * 132 + i] = v.y;
            At[(jj + 2) * 132 + i] = v.z; At[(jj + 3) * 132 + i] = v.w;
        }
    } else {
        // At[i][j] = EA[c0+i][j] (natural rows)
#pragma unroll
        for (int q = 0; q < 2; ++q) {
            int idx = t + q * 256;
            int cl = idx >> 5;                // 0..15
            int col4 = (idx & 31) * 4;        // 0..124
            *(float4*)&At[cl * 132 + col4] =
                *(const float4*)&EA[(size_t)(c0 + cl) * S_ + col4];
        }
    }
    // ---- stage Bs ----
    {
        int cl = t >> 4;                      // 0..15
        int k4 = (t & 15) * 4;                // 0..60
        *(float4*)&Bs[cl * 68 + k4] =
            *(const float4*)&Bsrc[(size_t)(c0 + cl) * S_ + kk0 + k4];
    }
    __syncthreads();

    // ---- main contraction: 8x4 tile, 16 c-iters ----
    int r0 = (t >> 4) * 8;                    // 128 rows
    int k0 = (t & 15) * 4;                    // 64 κ
    float acc[8][4] = {};
#pragma unroll
    for (int c = 0; c < 16; ++c) {
        float4 a0 = *(const float4*)&At[c * 132 + r0];
        float4 a1 = *(const float4*)&At[c * 132 + r0 + 4];
        float4 bv = *(const float4*)&Bs[c * 68 + k0];
        float av[8] = {a0.x, a0.y, a0.z, a0.w, a1.x, a1.y, a1.z, a1.w};
#pragma unroll
        for (int x = 0; x < 8; ++x) {
            acc[x][0] += av[x] * bv.x; acc[x][1] += av[x] * bv.y;
            acc[x][2] += av[x] * bv.z; acc[x][3] += av[x] * bv.w;
        }
    }

    // ---- epilogue: weight from global E, row/col sums ----
    float rs[8], cs[4] = {0.f, 0.f, 0.f, 0.f};
#pragma unroll
    for (int x = 0; x < 8; ++x) {
        float4 w = *(const float4*)&Wsrc[(size_t)(r0 + x) * S_ + kk0 + k0];
        float v0 = w.x * acc[x][0], v1 = w.y * acc[x][1];
        float v2 = w.z * acc[x][2], v3 = w.w * acc[x][3];
        rs[x] = v0 + v1 + v2 + v3;
        cs[0] += v0; cs[1] += v1; cs[2] += v2; cs[3] += v3;
    }
    // row sums -> m1/m2 partial slot (agent-scope sc1 stores, disjoint)
#pragma unroll
    for (int x = 0; x < 8; ++x) {
        rs[x] += __shfl_xor(rs[x], 1);
        rs[x] += __shfl_xor(rs[x], 2);
        rs[x] += __shfl_xor(rs[x], 4);
        rs[x] += __shfl_xor(rs[x], 8);
    }
    if ((t & 15) == 0) {
        float* MO = job ? m2p : m1p;
        size_t base = ((size_t)b * 16 + cc * 2 + kh) * S_ + r0;
#pragma unroll
        for (int x = 0; x < 8; ++x)
            __hip_atomic_store(&MO[base + x], rs[x], __ATOMIC_RELAXED,
                               __HIP_MEMORY_SCOPE_AGENT);
    }
    // col sums -> m3 partial slot (job0 only)
    if (!job) {
#pragma unroll
        for (int y = 0; y < 4; ++y) {
            cs[y] += __shfl_xor(cs[y], 16);
            cs[y] += __shfl_xor(cs[y], 32);
        }
        __syncthreads();                      // At reads done; reuse as red[4][64]
        if ((t & 63) < 16) {
            int w = t >> 6;
            *(float4*)&red[w * 64 + k0] = make_float4(cs[0], cs[1], cs[2], cs[3]);
        }
        __syncthreads();
        if (t < 64)
            __hip_atomic_store(&m3p[((size_t)b * 8 + cc) * S_ + kk0 + t],
                               red[t] + red[64 + t] + red[128 + t] + red[192 + t],
                               __ATOMIC_RELAXED, __HIP_MEMORY_SCOPE_AGENT);
    }

    // ---- release: each thread drains its stores, then count this block ----
    asm volatile("s_waitcnt vmcnt(0)" ::: "memory");
    __syncthreads();
    if (t == 0)
        lastflag = (__hip_atomic_fetch_add(&cnt[b], 1u, __ATOMIC_ACQ_REL,
                                           __HIP_MEMORY_SCOPE_AGENT) == 31u) ? 1 : 0;
    __syncthreads();

    // ---- phase C: last block of batch b produces the output ----
    if (lastflag) {
        float* Vs = pool;                // [128][33]
        float* ms = pool + 4224;         // [3][128]
        float* zr = pool + 4608;         // [4]
        const float* Vb = V + (size_t)b * S_ * F_;
#pragma unroll
        for (int q = 0; q < 4; ++q) {
            int idx = t + q * 256;            // f4 idx 0..1023
            int row = idx >> 3, c4 = (idx & 7) * 4;
            float4 v = *(const float4*)&Vb[row * F_ + c4];
            Vs[row * 33 + c4 + 0] = v.x; Vs[row * 33 + c4 + 1] = v.y;
            Vs[row * 33 + c4 + 2] = v.z; Vs[row * 33 + c4 + 3] = v.w;
        }
        float v1 = 0.f;
        if (t < S_) {
            size_t b16 = (size_t)b * 16 * S_ + t;
            float v2 = 0.f, v3 = 0.f;
#pragma unroll
            for (int p = 0; p < 16; ++p) {
                v1 += __hip_atomic_load(&m1p[b16 + p * S_], __ATOMIC_RELAXED,
                                        __HIP_MEMORY_SCOPE_AGENT);
                v2 += __hip_atomic_load(&m2p[b16 + p * S_], __ATOMIC_RELAXED,
                                        __HIP_MEMORY_SCOPE_AGENT);
            }
            size_t b8 = (size_t)b * 8 * S_ + t;
#pragma unroll
            for (int p = 0; p < 8; ++p)
                v3 += __hip_atomic_load(&m3p[b8 + p * S_], __ATOMIC_RELAXED,
                                        __HIP_MEMORY_SCOPE_AGENT);
            ms[t] = v1; ms[S_ + t] = v2; ms[2 * S_ + t] = v3;
        }
        float z = v1;
#pragma unroll
        for (int off = 32; off; off >>= 1) z += __shfl_xor(z, off);
        if ((t & 63) == 0) zr[t >> 6] = z;
        __syncthreads();
        float invZ = 1.0f / (zr[0] + zr[1] + zr[2] + zr[3]);
        if (t < 96) {
            int which = t >> 5, f = t & 31;
            const float* ml = &ms[which * S_];
            float s = 0.f;
#pragma unroll 8
            for (int s0 = 0; s0 < S_; ++s0) s += ml[s0] * Vs[s0 * 33 + f];
            out[(size_t)b * 96 + t] = s * invZ;
        }
    }
}

extern "C" void kernel_launch(void* const* d_in, const int* in_sizes, int n_in,
                              void* d_out, int out_size, void* d_ws, size_t ws_size,
                              hipStream_t stream) {
    const float* X  = (const float*)d_in[0];
    const float* V  = (const float*)d_in[1];
    const float* W1 = (const float*)d_in[2];
    const float* b1 = (const float*)d_in[3];
    const float* W2 = (const float*)d_in[4];
    const float* b2 = (const float*)d_in[5];
    const float* W3 = (const float*)d_in[6];
    const float* b3 = (const float*)d_in[7];
    float* out = (float*)d_out;

    float* E   = (float*)d_ws;                     // [B][3][S][S]
    float* m1p = E + (size_t)B_ * 3 * S_ * S_;     // [B][16][S]
    float* m2p = m1p + (size_t)B_ * 16 * S_;       // [B][16][S]
    float* m3p = m2p + (size_t)B_ * 16 * S_;       // [B][8][S]
    unsigned int* cnt = (unsigned int*)(m3p + (size_t)B_ * 8 * S_);  // [B]

    k_qe<<<B_ * 12, 256, 0, stream>>>(X, W1, b1, W2, b2, W3, b3, E, cnt);
    k_marg<<<1024, 256, 0, stream>>>(E, m1p, m2p, m3p, V, out, cnt);
}

// Round 15
// 19.890 us; speedup vs baseline: 1.6951x; 1.6951x over previous
//
#include <hip/hip_runtime.h>
#include <hip/hip_bf16.h>

// ThreeWayAttention: B=32, S=128, D=32, F=32, U=11
// p_ijk ∝ EA[i,j]·EB[j,k]·EC[i,k], EX = exp(X/9), diagonals = 0.
// E computed ONCE in k_qe (global, 6.3 MB, XCD-L2-resident: all kernels map
// batch b to XCD b%8 via b = bid&31).
// k_marg per block (b, job, cc=c-chunk of 16, kh=κ-half of 64):
//   job0: acc[i,κ]=Σ_{j∈cc} EA[i,j]EB[j,κ]; v=EC⊙acc → m1 rows, m3 cols
//   job1: acc[j,κ]=Σ_{i∈cc} EA[i,j]EC[i,κ]; v=EB⊙acc → m2 rows
// out = [m1@V, m2@V, m3@V]/Z, Z = Σ m1.
// NOTE (R9/R10/R14): in-kernel cross-block completion (fences / atomics /
// sc1 stores) costs 4-55 µs on multi-XCD — kernel boundaries are cheaper.

#define B_ 32
#define S_ 128
#define D_ 32
#define F_ 32
#define U_ 11
#define INV9 (1.0f / 9.0f)

// ---------------- Kernel 1: Q projections + E tiles (once) ----------------
// grid: 384 = rest*32 + b  (b, m=rest>>2, 32-row i-tile=rest&3), 256 threads.
// bid%8 == b%8 -> E written on XCD b%8 (same XCD k_marg reads it from).
__global__ __launch_bounds__(256) void k_qe(const float* __restrict__ X,
    const float* __restrict__ W1, const float* __restrict__ b1,
    const float* __restrict__ W2, const float* __restrict__ b2,
    const float* __restrict__ W3, const float* __restrict__ b3,
    float* __restrict__ E) {
    int blk = blockIdx.x;
    int b = blk & 31;
    int rest = blk >> 5;               // 0..11
    int m = rest >> 2;   // 0:EA(Q1,Q2) 1:EB(Q2,Q3) 2:EC(Q1,Q3)
    int tl = rest & 3;   // 32-row tile
    __shared__ float Wt[2][U_][32];    // [side][u][d]
    __shared__ float bsh[2][U_];
    __shared__ float QRt[U_][S_];      // [u][j]
    __shared__ float QLt[U_][32];      // [u][il]
    int t = threadIdx.x;

    const float* WL = (m == 0) ? W1 : (m == 1) ? W2 : W1;
    const float* WR = (m == 0) ? W2 : (m == 1) ? W3 : W3;
    const float* bL = (m == 0) ? b1 : (m == 1) ? b2 : b1;
    const float* bR = (m == 0) ? b2 : (m == 1) ? b3 : b3;
    for (int idx = t; idx < 704; idx += 256) {
        int side = idx >= 352;
        int r = idx - side * 352;
        int u = r >> 5, d = r & 31;
        Wt[side][u][d] = (side ? WR : WL)[d * U_ + u];
    }
    if (t < 22) {
        int side = t >= U_;
        int u = side ? t - U_ : t;
        bsh[side][u] = (side ? bR : bL)[u];
    }
    __syncthreads();

    if (t < 160) {
        int isR = (t < 128);
        int row = isR ? t : (tl * 32 + (t - 128));
        const float* Xr = X + ((size_t)b * S_ + row) * D_;
        float4 xv[8];
#pragma unroll
        for (int q = 0; q < 8; ++q) xv[q] = ((const float4*)Xr)[q];
        float qv[U_];
#pragma unroll
        for (int u = 0; u < U_; ++u) qv[u] = bsh[isR][u];
#pragma unroll
        for (int d4 = 0; d4 < 8; ++d4) {
            float4 x = xv[d4];
#pragma unroll
            for (int u = 0; u < U_; ++u) {
                float4 w = *(const float4*)&Wt[isR][u][d4 * 4];
                qv[u] += x.x * w.x + x.y * w.y + x.z * w.z + x.w * w.w;
            }
        }
        if (isR) {
#pragma unroll
            for (int u = 0; u < U_; ++u) QRt[u][t] = qv[u];
        } else {
#pragma unroll
            for (int u = 0; u < U_; ++u) QLt[u][t - 128] = qv[u];
        }
    }
    __syncthreads();

    // E phase: thread owns fixed j4; QR fragment cached in registers.
    float* Eb = E + (size_t)(b * 3 + m) * (S_ * S_);
    int j4 = (t & 31) * 4;
    int il0 = (t >> 5) * 4;
    float4 qr[U_];
#pragma unroll
    for (int u = 0; u < U_; ++u) qr[u] = *(const float4*)&QRt[u][j4];
#pragma unroll
    for (int q = 0; q < 4; ++q) {
        int il = il0 + q;
        int i = tl * 32 + il;
        float s0 = 0, s1 = 0, s2 = 0, s3v = 0;
#pragma unroll
        for (int u = 0; u < U_; ++u) {
            float ql = QLt[u][il];
            s0 += ql * qr[u].x; s1 += ql * qr[u].y;
            s2 += ql * qr[u].z; s3v += ql * qr[u].w;
        }
        float4 e;
        e.x = (j4 + 0 == i) ? 0.f : __expf(s0 * INV9);
        e.y = (j4 + 1 == i) ? 0.f : __expf(s1 * INV9);
        e.z = (j4 + 2 == i) ? 0.f : __expf(s2 * INV9);
        e.w = (j4 + 3 == i) ? 0.f : __expf(s3v * INV9);
        *(float4*)&Eb[(size_t)i * S_ + j4] = e;
    }
}

// ---------------- Kernel 2: marginals (exp-free, high-occupancy) ----------------
// grid: 1024 = kh*512 + cc*64 + job*32 + b, 256 threads, 8x4 tile.
__global__ __launch_bounds__(256, 4) void k_marg(const float* __restrict__ E,
    float* __restrict__ m1p, float* __restrict__ m2p, float* __restrict__ m3p) {
    int bid = blockIdx.x;
    int b   = bid & 31;
    int job = (bid >> 5) & 1;
    int cc  = (bid >> 6) & 7;          // 8 chunks of 16
    int kh  = bid >> 9;                // 0..1
    int c0  = cc * 16, kk0 = kh * 64;
    const float* EA = E + (size_t)b * 3 * S_ * S_;
    const float* EB = EA + S_ * S_;
    const float* EC = EB + S_ * S_;
    const float* Bsrc = job ? EC : EB;
    const float* Wsrc = job ? EB : EC;

    __shared__ float At[16][132];      // [c][r]
    __shared__ float Bs[16][68];       // [c][κ]
    float* red = &At[0][0];            // alias for m3 cross-wave reduce [4][64]

    int t = threadIdx.x;

    // ---- stage At ----
    if (job == 0) {
        // At[j][i] = EA[i][c0+j] (transpose in LDS; 2-way write conflict = free)
#pragma unroll
        for (int q = 0; q < 2; ++q) {
            int idx = t + q * 256;            // f4 idx 0..511
            int i = idx >> 2;                 // 0..127
            int j4 = (idx & 3) * 4;           // 0..12
            float4 v = *(const float4*)&EA[(size_t)i * S_ + c0 + j4];
            At[j4 + 0][i] = v.x; At[j4 + 1][i] = v.y;
            At[j4 + 2][i] = v.z; At[j4 + 3][i] = v.w;
        }
    } else {
        // At[i][j] = EA[c0+i][j] (natural rows)
#pragma unroll
        for (int q = 0; q < 2; ++q) {
            int idx = t + q * 256;
            int cl = idx >> 5;                // 0..15
            int col4 = (idx & 31) * 4;        // 0..124
            *(float4*)&At[cl][col4] =
                *(const float4*)&EA[(size_t)(c0 + cl) * S_ + col4];
        }
    }
    // ---- stage Bs ----
    {
        int cl = t >> 4;                      // 0..15
        int k4 = (t & 15) * 4;                // 0..60
        *(float4*)&Bs[cl][k4] =
            *(const float4*)&Bsrc[(size_t)(c0 + cl) * S_ + kk0 + k4];
    }
    __syncthreads();

    // ---- main contraction: 8x4 tile, 16 c-iters ----
    int r0 = (t >> 4) * 8;                    // 128 rows
    int k0 = (t & 15) * 4;                    // 64 κ
    float acc[8][4] = {};
#pragma unroll
    for (int c = 0; c < 16; ++c) {
        float4 a0 = *(const float4*)&At[c][r0];
        float4 a1 = *(const float4*)&At[c][r0 + 4];
        float4 bv = *(const float4*)&Bs[c][k0];
        float av[8] = {a0.x, a0.y, a0.z, a0.w, a1.x, a1.y, a1.z, a1.w};
#pragma unroll
        for (int x = 0; x < 8; ++x) {
            acc[x][0] += av[x] * bv.x; acc[x][1] += av[x] * bv.y;
            acc[x][2] += av[x] * bv.z; acc[x][3] += av[x] * bv.w;
        }
    }

    // ---- epilogue: weight from global E, row/col sums ----
    float rs[8], cs[4] = {0.f, 0.f, 0.f, 0.f};
#pragma unroll
    for (int x = 0; x < 8; ++x) {
        float4 w = *(const float4*)&Wsrc[(size_t)(r0 + x) * S_ + kk0 + k0];
        float v0 = w.x * acc[x][0], v1 = w.y * acc[x][1];
        float v2 = w.z * acc[x][2], v3 = w.w * acc[x][3];
        rs[x] = v0 + v1 + v2 + v3;
        cs[0] += v0; cs[1] += v1; cs[2] += v2; cs[3] += v3;
    }
    // row sums -> m1/m2 partial (reduce over 16 κ-lane-groups)
#pragma unroll
    for (int x = 0; x < 8; ++x) {
        rs[x] += __shfl_xor(rs[x], 1);
        rs[x] += __shfl_xor(rs[x], 2);
        rs[x] += __shfl_xor(rs[x], 4);
        rs[x] += __shfl_xor(rs[x], 8);
    }
    if ((t & 15) == 0) {
        float* MO = job ? m2p : m1p;
        size_t base = ((size_t)b * 16 + cc * 2 + kh) * S_ + r0;
#pragma unroll
        for (int x = 0; x < 8; ++x) MO[base + x] = rs[x];
    }
    // col sums -> m3 partial (job0 only)
    if (!job) {
#pragma unroll
        for (int y = 0; y < 4; ++y) {
            cs[y] += __shfl_xor(cs[y], 16);
            cs[y] += __shfl_xor(cs[y], 32);
        }
        __syncthreads();                      // At reads done; reuse as red[4][64]
        if ((t & 63) < 16) {
            int w = t >> 6;
            *(float4*)&red[w * 64 + k0] = make_float4(cs[0], cs[1], cs[2], cs[3]);
        }
        __syncthreads();
        if (t < 64)
            m3p[((size_t)b * 8 + cc) * S_ + kk0 + t] =
                red[t] + red[64 + t] + red[128 + t] + red[192 + t];
    }
}

// ---------------- Kernel 3: gather partials, normalize, V matmul ----------------
__global__ __launch_bounds__(128) void k_out(const float* __restrict__ m1p,
    const float* __restrict__ m2p, const float* __restrict__ m3p,
    const float* __restrict__ V, float* __restrict__ out) {
    int b = blockIdx.x, t = threadIdx.x;
    __shared__ float ms[3][S_];
    __shared__ float Vs[S_][33];
    __shared__ float zr[2];
    const float* Vb = V + (size_t)b * S_ * F_;
#pragma unroll
    for (int q = 0; q < 8; ++q) {
        int idx = t + q * 128;            // float4 idx 0..1023
        int row = idx >> 3, c4 = (idx & 7) * 4;
        float4 v = *(const float4*)&Vb[row * F_ + c4];
        Vs[row][c4 + 0] = v.x; Vs[row][c4 + 1] = v.y;
        Vs[row][c4 + 2] = v.z; Vs[row][c4 + 3] = v.w;
    }
    size_t b16 = (size_t)b * 16 * S_ + t;
    float v1 = 0.f, v2 = 0.f;
#pragma unroll
    for (int p = 0; p < 16; ++p) {
        v1 += m1p[b16 + p * S_];
        v2 += m2p[b16 + p * S_];
    }
    size_t b8 = (size_t)b * 8 * S_ + t;
    float v3 = 0.f;
#pragma unroll
    for (int p = 0; p < 8; ++p) v3 += m3p[b8 + p * S_];
    ms[0][t] = v1; ms[1][t] = v2; ms[2][t] = v3;
    float z = v1;
#pragma unroll
    for (int off = 32; off; off >>= 1) z += __shfl_xor(z, off);
    if ((t & 63) == 0) zr[t >> 6] = z;
    __syncthreads();
    float invZ = 1.0f / (zr[0] + zr[1]);
    if (t < 96) {
        int which = t >> 5, f = t & 31;
        const float* ml = &ms[which][0];
        float s = 0.f;
#pragma unroll 8
        for (int s0 = 0; s0 < S_; ++s0) s += ml[s0] * Vs[s0][f];
        out[(size_t)b * 96 + t] = s * invZ;
    }
}

extern "C" void kernel_launch(void* const* d_in, const int* in_sizes, int n_in,
                              void* d_out, int out_size, void* d_ws, size_t ws_size,
                              hipStream_t stream) {
    const float* X  = (const float*)d_in[0];
    const float* V  = (const float*)d_in[1];
    const float* W1 = (const float*)d_in[2];
    const float* b1 = (const float*)d_in[3];
    const float* W2 = (const float*)d_in[4];
    const float* b2 = (const float*)d_in[5];
    const float* W3 = (const float*)d_in[6];
    const float* b3 = (const float*)d_in[7];
    float* out = (float*)d_out;

    float* E   = (float*)d_ws;                     // [B][3][S][S]
    float* m1p = E + (size_t)B_ * 3 * S_ * S_;     // [B][16][S]
    float* m2p = m1p + (size_t)B_ * 16 * S_;       // [B][16][S]
    float* m3p = m2p + (size_t)B_ * 16 * S_;       // [B][8][S]

    k_qe<<<B_ * 12, 256, 0, stream>>>(X, W1, b1, W2, b2, W3, b3, E);
    k_marg<<<1024, 256, 0, stream>>>(E, m1p, m2p, m3p);
    k_out<<<B_, 128, 0, stream>>>(m1p, m2p, m3p, V, out);
}